// Round 7
// baseline (2159.748 us; speedup 1.0000x reference)
//
#include <hip/hip_runtime.h>

#define B_ 256
#define T_ 256
#define E_ 512
#define V_ 32000
#define NMOV 16
#define NT 65              // column tiles: A(32) | Wv(32) | Wqk(1)
#define NCG 16             // column groups
#define NBG 16             // batch groups
#define YSTR 1056          // Y exchange row stride (bf16 units)
#define ZSTR 520           // k_logits LDS stride

#define SQRTE 22.62741699796952f
#define SCALE 0.04419417382415922f   // 1/sqrt(512)

typedef __attribute__((ext_vector_type(8))) short bf16x8;
typedef __attribute__((ext_vector_type(4))) short bf16x4;
typedef __attribute__((ext_vector_type(4))) float f32x4;
typedef unsigned long long u64;

__device__ __forceinline__ short f2bf(float f) {
  unsigned u = __float_as_uint(f);
  u += 0x7fffu + ((u >> 16) & 1u);          // RNE
  return (short)(u >> 16);
}
__device__ __forceinline__ float bf2f(short s) {
  return __uint_as_float(((unsigned)(unsigned short)s) << 16);
}

// full-wave64 sum -> uniform scalar (DPP butterfly + readlane)
__device__ __forceinline__ float wredsum(float v) {
  int x;
  x = __builtin_amdgcn_update_dpp(0, __float_as_int(v), 0xB1, 0xF, 0xF, true);
  v += __int_as_float(x);
  x = __builtin_amdgcn_update_dpp(0, __float_as_int(v), 0x4E, 0xF, 0xF, true);
  v += __int_as_float(x);
  x = __builtin_amdgcn_update_dpp(0, __float_as_int(v), 0x141, 0xF, 0xF, true);
  v += __int_as_float(x);
  x = __builtin_amdgcn_update_dpp(0, __float_as_int(v), 0x140, 0xF, 0xF, true);
  v += __int_as_float(x);
  x = __builtin_amdgcn_update_dpp(0, __float_as_int(v), 0x142, 0xF, 0xF, true);
  v += __int_as_float(x);
  x = __builtin_amdgcn_update_dpp(0, __float_as_int(v), 0x143, 0xF, 0xF, true);
  v += __int_as_float(x);
  return __int_as_float(__builtin_amdgcn_readlane(__float_as_int(v), 63));
}
// row-of-16 butterfly reductions (every lane gets its row's result)
__device__ __forceinline__ float rowmax16(float v) {
  int x;
  x = __builtin_amdgcn_update_dpp(0, __float_as_int(v), 0xB1, 0xF, 0xF, true);
  v = fmaxf(v, __int_as_float(x));
  x = __builtin_amdgcn_update_dpp(0, __float_as_int(v), 0x4E, 0xF, 0xF, true);
  v = fmaxf(v, __int_as_float(x));
  x = __builtin_amdgcn_update_dpp(0, __float_as_int(v), 0x141, 0xF, 0xF, true);
  v = fmaxf(v, __int_as_float(x));
  x = __builtin_amdgcn_update_dpp(0, __float_as_int(v), 0x140, 0xF, 0xF, true);
  v = fmaxf(v, __int_as_float(x));
  return v;
}
__device__ __forceinline__ float rowsum16(float v) {
  int x;
  x = __builtin_amdgcn_update_dpp(0, __float_as_int(v), 0xB1, 0xF, 0xF, true);
  v += __int_as_float(x);
  x = __builtin_amdgcn_update_dpp(0, __float_as_int(v), 0x4E, 0xF, 0xF, true);
  v += __int_as_float(x);
  x = __builtin_amdgcn_update_dpp(0, __float_as_int(v), 0x141, 0xF, 0xF, true);
  v += __int_as_float(x);
  x = __builtin_amdgcn_update_dpp(0, __float_as_int(v), 0x140, 0xF, 0xF, true);
  v += __int_as_float(x);
  return v;
}
__device__ __forceinline__ float rdlane(float v, int lane) {
  return __int_as_float(__builtin_amdgcn_readlane(__float_as_int(v), lane));
}

// relaxed agent-scope (coherence-point) helpers — no cache maintenance
__device__ __forceinline__ bf16x8 aload8v(const short* p) {
  union { u64 u[2]; bf16x8 v; } c;
  c.u[0] = __hip_atomic_load((const u64*)p,       __ATOMIC_RELAXED, __HIP_MEMORY_SCOPE_AGENT);
  c.u[1] = __hip_atomic_load((const u64*)(p + 4), __ATOMIC_RELAXED, __HIP_MEMORY_SCOPE_AGENT);
  return c.v;
}
__device__ __forceinline__ void astore4v(short* p, bf16x4 v) {
  union { bf16x4 v; u64 u; } c; c.v = v;
  __hip_atomic_store((u64*)p, c.u, __ATOMIC_RELAXED, __HIP_MEMORY_SCOPE_AGENT);
}

// ---------------- K1: mover K/V: Km = mover@Wk + bk, Vm = mover@Wv + bv ----
__global__ void k_movers(const float* __restrict__ Wk, const float* __restrict__ bk,
                         const float* __restrict__ Wv, const float* __restrict__ bv,
                         const float* __restrict__ mover, float* __restrict__ kmvm)
{
  const int m = blockIdx.x & 15;
  const int s = blockIdx.x >> 4;              // 0 -> K, 1 -> V
  const float* W  = s ? Wv : Wk;
  const float* bb = s ? bv : bk;
  const int c = threadIdx.x * 2;
  float a0 = bb[c], a1 = bb[c + 1];
  for (int r = 0; r < E_; ++r) {
    float mv = mover[m * E_ + r];
    float2 wv = *(const float2*)(W + (size_t)r * E_ + c);
    a0 += mv * wv.x; a1 += mv * wv.y;
  }
  kmvm[(s * NMOV + m) * E_ + c]     = a0;
  kmvm[(s * NMOV + m) * E_ + c + 1] = a1;
}

// ---------------- K2: A = Wq @ Wk^T (bf16 MFMA, f32 out) -------------------
__global__ void k_gemmA(const float* __restrict__ Wq, const float* __restrict__ Wk,
                        float* __restrict__ A)
{
  const int ti = blockIdx.x >> 5, tj = blockIdx.x & 31;
  const int l = threadIdx.x, r16 = l & 15, kq = (l >> 4) * 8;
  f32x4 acc = {0.f, 0.f, 0.f, 0.f};
  for (int ks = 0; ks < 16; ++ks) {
    const float* ap = Wq + (size_t)(ti * 16 + r16) * E_ + ks * 32 + kq;
    const float* bp = Wk + (size_t)(tj * 16 + r16) * E_ + ks * 32 + kq;
    bf16x8 a, b;
    #pragma unroll
    for (int j = 0; j < 8; ++j) { a[j] = f2bf(ap[j]); b[j] = f2bf(bp[j]); }
    acc = __builtin_amdgcn_mfma_f32_16x16x32_bf16(a, b, acc, 0, 0, 0);
  }
  #pragma unroll
  for (int r = 0; r < 4; ++r)
    A[(size_t)(ti * 16 + (l >> 4) * 4 + r) * E_ + tj * 16 + r16] = acc[r];
}

// ---------------- K3: Wqk[i][m] = sum_j Wq[i][j] * Km[m][j] ----------------
__global__ void k_wqk(const float* __restrict__ Wq, const float* __restrict__ kmvm,
                      float* __restrict__ Wqk)
{
  const int i = blockIdx.x;
  const int l = threadIdx.x, m = l & 15, sl = l >> 4;
  float p = 0.f;
  for (int j = sl * 128; j < sl * 128 + 128; ++j)
    p += Wq[(size_t)i * E_ + j] * kmvm[(size_t)m * E_ + j];
  p += __shfl_xor(p, 16, 64);
  p += __shfl_xor(p, 32, 64);
  if (l < 16) Wqk[i * 16 + m] = p;
}

// ---------------- K4: cvec[i] = Wq[i]·bk + Wk[i]·bq ------------------------
__global__ void k_cvec(const float* __restrict__ Wq, const float* __restrict__ Wk,
                       const float* __restrict__ bq, const float* __restrict__ bk,
                       float* __restrict__ cvec)
{
  const int i = blockIdx.x * 64 + threadIdx.x;
  float s = 0.f;
  for (int j = 0; j < E_; ++j)
    s += Wq[(size_t)i * E_ + j] * bk[j] + Wk[(size_t)i * E_ + j] * bq[j];
  cvec[i] = s;
}

// ---------------- K5: lb[m] = bq·Km[m] (m<16), lb[16] = bq·bk --------------
__global__ void k_lb(const float* __restrict__ bq, const float* __restrict__ bk,
                     const float* __restrict__ kmvm, float* __restrict__ lb)
{
  const int l = threadIdx.x;
  if (l < 16) {
    float s = 0.f;
    for (int j = 0; j < E_; ++j) s += bq[j] * kmvm[(size_t)l * E_ + j];
    lb[l] = s;
  } else if (l == 16) {
    float s = 0.f;
    for (int j = 0; j < E_; ++j) s += bq[j] * bk[j];
    lb[16] = s;
  }
}

// ---------------- K6: pack Wcat = [A | Wv | Wqk] into MFMA fragment order --
__global__ void k_pack(const float* __restrict__ A, const float* __restrict__ Wv,
                       const float* __restrict__ Wqk, short* __restrict__ Wfrag)
{
  const int blk = blockIdx.x;          // ct*16 + ks
  const int ct = blk >> 4, ks = blk & 15;
  const int l = threadIdx.x;
  const int c = ct * 16 + (l & 15);
  const int r0 = ks * 32 + (l >> 4) * 8;
  short v[8];
  #pragma unroll
  for (int j = 0; j < 8; ++j) {
    const int r = r0 + j;
    float x;
    if (c < 512)       x = A[(size_t)r * E_ + c];
    else if (c < 1024) x = Wv[(size_t)r * E_ + (c - 512)];
    else               x = Wqk[r * 16 + (c - 1024)];
    v[j] = f2bf(x);
  }
  *(bf16x8*)(Wfrag + ((size_t)blk * 64 + l) * 8) = *(const bf16x8*)v;
}

// ---------------- phase B: softmax + PV(MFMA) + LN + next-z staging --------
__device__ __forceinline__ void phase_b(
    int p, int bg, int l, int w,
    const short* __restrict__ Yx, short* attf, short* umov,
    const short* vmfragT, short* zfs_s,
    float (&zr)[2][8],
    const float* cw, const float* bw, const float* gw, const float* bbv,
    float lbw, float lb16,
    const float* xa, const float* xb, bool addx)
{
  const int lm = l & 15;
  const short* Yb  = Yx + ((size_t)(p * NBG + bg) * 16) * YSTR;
  const short* Yr0 = Yb + (size_t)(w * 2) * YSTR;
  const short* Yr1 = Yb + (size_t)(w * 2 + 1) * YSTR;
  bf16x8 wv0 = aload8v(Yr0 + l * 8),       wv1 = aload8v(Yr1 + l * 8);
  bf16x8 vv0 = aload8v(Yr0 + 512 + l * 8), vv1 = aload8v(Yr1 + 512 + l * 8);
  const short* Yrh = (l < 32) ? Yr0 : Yr1;
  short mlr = (short)__hip_atomic_load((const short*)(Yrh + 1024 + lm),
                                       __ATOMIC_RELAXED, __HIP_MEMORY_SCOPE_AGENT);

  // q.k0 dots (full-wave reductions)
  float p0 = 0.f, p1 = 0.f;
  #pragma unroll
  for (int j = 0; j < 8; ++j) {
    p0 += (bf2f(wv0[j]) + cw[j]) * zr[0][j];
    p1 += (bf2f(wv1[j]) + cw[j]) * zr[1][j];
  }
  const float dl0 = (wredsum(p0) + lb16) * SCALE;
  const float dl1 = (wredsum(p1) + lb16) * SCALE;

  // lane-parallel softmax over 16 movers + scalar k0 term
  const float dl   = (l < 32) ? dl0 : dl1;
  const float lgt  = (bf2f(mlr) + lbw) * SCALE;
  const float mx   = fmaxf(rowmax16(lgt), dl);
  const float e    = __expf(lgt - mx);
  const float a0v  = __expf(dl - mx);
  const float den  = rowsum16(e) + a0v;
  if ((l & 16) == 0)
    attf[(w * 2 + (l >> 5)) * 40 + lm] = f2bf(e);

  const float a00 = rdlane(a0v, 0),  a01 = rdlane(a0v, 32);
  const float rd0 = __fdividef(1.f, rdlane(den, 0));
  const float rd1 = __fdividef(1.f, rdlane(den, 32));

  __syncthreads();                              // barB1: attf ready

  // PV: 4 col-tiles per wave, D[row=ucol][col=batch] -> umov (bf16)
  #pragma unroll
  for (int tt = 0; tt < 4; ++tt) {
    const int tile = w * 4 + tt;
    bf16x8 af = {0, 0, 0, 0, 0, 0, 0, 0};
    if (l < 32) af = *(const bf16x8*)&vmfragT[((size_t)tile * 32 + l) * 8];
    bf16x8 bf = *(const bf16x8*)&attf[lm * 40 + (l >> 4) * 8];
    f32x4 z4 = {0.f, 0.f, 0.f, 0.f};
    z4 = __builtin_amdgcn_mfma_f32_16x16x32_bf16(af, bf, z4, 0, 0, 0);
    bf16x4 o4;
    #pragma unroll
    for (int r = 0; r < 4; ++r) o4[r] = f2bf(z4[r]);
    *(bf16x4*)&umov[(size_t)lm * 528 + tile * 16 + ((l >> 4) << 2)] = o4;
  }
  __syncthreads();                              // barB2: umov ready

  // owner combine + LayerNorm + next-z staging
  {
    bf16x8 um0 = *(const bf16x8*)&umov[(size_t)(w * 2) * 528 + l * 8];
    bf16x8 um1 = *(const bf16x8*)&umov[(size_t)(w * 2 + 1) * 528 + l * 8];
    float u0[8], u1[8];
    #pragma unroll
    for (int j = 0; j < 8; ++j) {
      u0[j] = zr[0][j] + (a00 * (bf2f(vv0[j]) + bw[j]) + bf2f(um0[j])) * rd0;
      u1[j] = zr[1][j] + (a01 * (bf2f(vv1[j]) + bw[j]) + bf2f(um1[j])) * rd1;
    }
    float s10 = 0.f, s20 = 0.f, s11 = 0.f, s21 = 0.f;
    #pragma unroll
    for (int j = 0; j < 8; ++j) {
      s10 += u0[j]; s20 += u0[j] * u0[j];
      s11 += u1[j]; s21 += u1[j] * u1[j];
    }
    s10 = wredsum(s10); s20 = wredsum(s20);
    s11 = wredsum(s11); s21 = wredsum(s21);
    const float mean0 = s10 * (1.f / 512.f);
    const float mean1 = s11 * (1.f / 512.f);
    const float rstd0 = rsqrtf(s20 * (1.f / 512.f) - mean0 * mean0 + 1e-6f);
    const float rstd1 = rsqrtf(s21 * (1.f / 512.f) - mean1 * mean1 + 1e-6f);

    short ta[8], tb[8];
    #pragma unroll
    for (int j = 0; j < 8; ++j) {
      float z0 = (u0[j] - mean0) * rstd0 * gw[j] + bbv[j];
      float z1 = (u1[j] - mean1) * rstd1 * gw[j] + bbv[j];
      if (addx) { z0 += xa[j] * SQRTE; z1 += xb[j] * SQRTE; }
      zr[0][j] = z0; zr[1][j] = z1;
      ta[j] = f2bf(z0); tb[j] = f2bf(z1);
    }
    if (addx) {
      const int ks = l >> 2;
      const int ua = ((l & 3) << 4) | (w * 2);
      const int ub = ua | 1;
      *(bf16x8*)&zfs_s[((ks << 6) + (ua ^ (ks & 7))) * 8] = *(const bf16x8*)ta;
      *(bf16x8*)&zfs_s[((ks << 6) + (ub ^ (ks & 7))) * 8] = *(const bf16x8*)tb;
    }
  }
}

// ---------------- K7: dual-bg scan: fill fabric wait with 2nd batch-group --
// 128 WGs = 16 cg x 8 bg-pairs (bgA=bgp, bgB=bgp+8), 512 threads (8 waves).
// Per step: [waves 0-3: MFMA bgA tiles | waves 4-7: MFMA bgB tiles] -> ack ->
// bar2 -> tid0 flags both bgs -> poll A (early-issue B flag load) ->
// phase B(bgA) (softmax+PV+LN+stage zfs[0]) -> check/poll B -> phase B(bgB)
// -> end barrier. bgB's exchange latency hides under phase B(bgA).
__global__ __launch_bounds__(512, 2) void k_scan7(
    const float* __restrict__ hidden, const int* __restrict__ seq,
    const float* __restrict__ emb,
    const float* __restrict__ gamma, const float* __restrict__ beta,
    const float* __restrict__ bv,
    const float* __restrict__ kmvm, const float* __restrict__ cvec,
    const float* __restrict__ lb, const short* __restrict__ Wfrag,
    short* __restrict__ Yx, unsigned* __restrict__ flags,
    float* __restrict__ zout)
{
  extern __shared__ char smem[];
  short* wlds    = (short*)smem;                  // 81920 B: <=5 weight tiles
  short* zfs     = (short*)(smem + 81920);        // 2 x 16384 B: z frags per bg-slot
  short* vmfragT = (short*)(smem + 114688);       // 16384 B: Vm^T A-frags [32][32][8]
  short* umov    = (short*)(smem + 131072);       // 16896 B: [16][528] bf16 (shared)
  short* attf    = (short*)(smem + 147968);       // 1280 B: [16][40] bf16 (shared)

  const int tid = threadIdx.x, l = tid & 63, w = tid >> 6;
  const int cg  = blockIdx.x >> 3;
  const int bgp = blockIdx.x & 7;
  const int bgA = bgp, bgB = bgp + 8;
  const int ntiles = (cg == 15) ? 5 : 4;
  const int lm = l & 15;

  // ---- stage constants ----
  for (int i = tid; i < 32 * 32; i += 512) {
    const int tile = i >> 5, ln = i & 31;
    const int m0 = (ln >> 4) * 8, c = tile * 16 + (ln & 15);
    short tmp[8];
    #pragma unroll
    for (int j = 0; j < 8; ++j)
      tmp[j] = f2bf(kmvm[NMOV * E_ + (size_t)(m0 + j) * E_ + c]);
    *(bf16x8*)&vmfragT[((size_t)tile * 32 + ln) * 8] = *(const bf16x8*)tmp;
  }
  for (int i = tid; i < 16 * 40; i += 512) attf[i] = 0;   // cols 16..39 stay 0
  {
    const bf16x8* src = (const bf16x8*)(Wfrag + (size_t)(cg * 4) * 16 * 64 * 8);
    bf16x8* dst = (bf16x8*)wlds;
    for (int i = tid; i < ntiles * 16 * 64; i += 512) dst[i] = src[i];
  }

  // ---- time-invariant per-lane vectors in registers ----
  float cw[8], bw[8], gw[8], bbv[8];
  *(float4*)&cw[0]  = *(const float4*)(cvec  + l * 8);
  *(float4*)&cw[4]  = *(const float4*)(cvec  + l * 8 + 4);
  *(float4*)&bw[0]  = *(const float4*)(bv    + l * 8);
  *(float4*)&bw[4]  = *(const float4*)(bv    + l * 8 + 4);
  *(float4*)&gw[0]  = *(const float4*)(gamma + l * 8);
  *(float4*)&gw[4]  = *(const float4*)(gamma + l * 8 + 4);
  *(float4*)&bbv[0] = *(const float4*)(beta  + l * 8);
  *(float4*)&bbv[4] = *(const float4*)(beta  + l * 8 + 4);
  const float lbw  = lb[lm];
  const float lb16 = lb[16];

  // ---- per-wave state: 2 batches per bg-slot ----
  const int b0A = bgA * 16 + w * 2;
  const int b0B = bgB * 16 + w * 2;
  float zrA[2][8], zrB[2][8];
  #pragma unroll
  for (int bi = 0; bi < 2; ++bi) {
    *(float4*)&zrA[bi][0] = *(const float4*)(hidden + (size_t)(b0A + bi) * E_ + l * 8);
    *(float4*)&zrA[bi][4] = *(const float4*)(hidden + (size_t)(b0A + bi) * E_ + l * 8 + 4);
    *(float4*)&zrB[bi][0] = *(const float4*)(hidden + (size_t)(b0B + bi) * E_ + l * 8);
    *(float4*)&zrB[bi][4] = *(const float4*)(hidden + (size_t)(b0B + bi) * E_ + l * 8 + 4);
  }

  // ---- x pipeline: 4 batches, direct emb gather one step ahead ----
  int sqb[4]; sqb[0] = b0A * T_; sqb[1] = sqb[0] + T_;
              sqb[2] = b0B * T_; sqb[3] = sqb[2] + T_;
  int ix[4];
  float4 exL[4], exH[4];
  #pragma unroll
  for (int k = 0; k < 4; ++k) ix[k] = seq[sqb[k]];
  #pragma unroll
  for (int k = 0; k < 4; ++k) {
    exL[k] = *(const float4*)(emb + (size_t)ix[k] * E_ + l * 8);
    exH[k] = *(const float4*)(emb + (size_t)ix[k] * E_ + l * 8 + 4);
  }
  // z0 = hidden + x0*sqrt(E); stage both slots
  {
    short t0[8], t1[8], t2[8], t3[8];
    float x0[8] = {exL[0].x, exL[0].y, exL[0].z, exL[0].w, exH[0].x, exH[0].y, exH[0].z, exH[0].w};
    float x1[8] = {exL[1].x, exL[1].y, exL[1].z, exL[1].w, exH[1].x, exH[1].y, exH[1].z, exH[1].w};
    float x2[8] = {exL[2].x, exL[2].y, exL[2].z, exL[2].w, exH[2].x, exH[2].y, exH[2].z, exH[2].w};
    float x3[8] = {exL[3].x, exL[3].y, exL[3].z, exL[3].w, exH[3].x, exH[3].y, exH[3].z, exH[3].w};
    #pragma unroll
    for (int j = 0; j < 8; ++j) {
      zrA[0][j] += x0[j] * SQRTE; t0[j] = f2bf(zrA[0][j]);
      zrA[1][j] += x1[j] * SQRTE; t1[j] = f2bf(zrA[1][j]);
      zrB[0][j] += x2[j] * SQRTE; t2[j] = f2bf(zrB[0][j]);
      zrB[1][j] += x3[j] * SQRTE; t3[j] = f2bf(zrB[1][j]);
    }
    const int ks = l >> 2;
    const int ua = ((l & 3) << 4) | (w * 2);
    const int ub = ua | 1;
    *(bf16x8*)&zfs[((ks << 6) + (ua ^ (ks & 7))) * 8]        = *(const bf16x8*)t0;
    *(bf16x8*)&zfs[((ks << 6) + (ub ^ (ks & 7))) * 8]        = *(const bf16x8*)t1;
    *(bf16x8*)&zfs[8192 + ((ks << 6) + (ua ^ (ks & 7))) * 8] = *(const bf16x8*)t2;
    *(bf16x8*)&zfs[8192 + ((ks << 6) + (ub ^ (ks & 7))) * 8] = *(const bf16x8*)t3;
  }
  #pragma unroll
  for (int k = 0; k < 4; ++k) ix[k] = seq[sqb[k] + 1];

  unsigned* const flA = flags + bgA * 32;     // one 128B line per bg
  unsigned* const flB = flags + bgB * 32;
  __syncthreads();                            // consts + zfs staged

  #pragma unroll 1
  for (int t = 0; t < T_; ++t) {
    const int p = t & 1;
    const unsigned rnd = (unsigned)(t + 1);
    const bool addx = (t + 1 < T_);

    // ---- issue x_{t+1} loads (land during the exchange) ----
    if (addx) {
      #pragma unroll
      for (int k = 0; k < 4; ++k) {
        exL[k] = *(const float4*)(emb + (size_t)ix[k] * E_ + l * 8);
        exH[k] = *(const float4*)(emb + (size_t)ix[k] * E_ + l * 8 + 4);
      }
      if (t + 2 < T_) {
        #pragma unroll
        for (int k = 0; k < 4; ++k) ix[k] = seq[sqb[k] + t + 2];
      }
    }

    // ---- phase A: waves 0-3 -> bgA tiles, waves 4-7 -> bgB tiles ----
    {
      const int slot = w >> 2;
      const int wl = w & 3;
      const int bgS = slot ? bgB : bgA;
      const short* zfs_s = zfs + slot * 8192;
      for (int lt = wl; lt < ntiles; lt += 4) {
        f32x4 acc = {0.f, 0.f, 0.f, 0.f};
        #pragma unroll
        for (int ks = 0; ks < 16; ++ks) {
          bf16x8 wf = *(const bf16x8*)&wlds[((lt * 16 + ks) * 64 + l) * 8];
          bf16x8 zb = *(const bf16x8*)&zfs_s[((ks << 6) + (l ^ (ks & 7))) * 8];
          acc = __builtin_amdgcn_mfma_f32_16x16x32_bf16(wf, zb, acc, 0, 0, 0);
        }
        const int gt = cg * 4 + lt;
        bf16x4 o;
        #pragma unroll
        for (int r = 0; r < 4; ++r) o[r] = f2bf(acc[r]);
        astore4v(Yx + (((size_t)(p * NBG + bgS) * 16) + lm) * YSTR
                    + gt * 16 + ((l >> 4) << 2), o);
      }
      asm volatile("s_waitcnt vmcnt(0)" ::: "memory");  // Y ACKed
    }
    __syncthreads();                          // bar2: all stores drained

    if (tid == 0) {
      __hip_atomic_store(&flA[cg], rnd, __ATOMIC_RELAXED, __HIP_MEMORY_SCOPE_AGENT);
      __hip_atomic_store(&flB[cg], rnd, __ATOMIC_RELAXED, __HIP_MEMORY_SCOPE_AGENT);
    }

    // ---- poll bgA flags (all waves; lanes 0-15 <-> cgs, skip own) ----
    for (;;) {
      unsigned f = __hip_atomic_load(&flA[lm], __ATOMIC_RELAXED, __HIP_MEMORY_SCOPE_AGENT);
      if (__all(lm == cg || f >= rnd)) break;
      __builtin_amdgcn_s_sleep(1);
    }
    asm volatile("" ::: "memory");

    // early-issue bgB flag load (checked after phase B(bgA))
    unsigned fB = __hip_atomic_load(&flB[lm], __ATOMIC_RELAXED, __HIP_MEMORY_SCOPE_AGENT);

    // ---- phase B (bgA) ----
    {
      float xa[8] = {exL[0].x, exL[0].y, exL[0].z, exL[0].w, exH[0].x, exH[0].y, exH[0].z, exH[0].w};
      float xb[8] = {exL[1].x, exL[1].y, exL[1].z, exL[1].w, exH[1].x, exH[1].y, exH[1].z, exH[1].w};
      phase_b(p, bgA, l, w, Yx, attf, umov, vmfragT, zfs, zrA,
              cw, bw, gw, bbv, lbw, lb16, xa, xb, addx);
    }

    // ---- confirm bgB flags (usually already set) ----
    if (!__all(lm == cg || fB >= rnd)) {
      for (;;) {
        unsigned f = __hip_atomic_load(&flB[lm], __ATOMIC_RELAXED, __HIP_MEMORY_SCOPE_AGENT);
        if (__all(lm == cg || f >= rnd)) break;
        __builtin_amdgcn_s_sleep(1);
      }
    }
    asm volatile("" ::: "memory");

    // ---- phase B (bgB) ----
    {
      float xa[8] = {exL[2].x, exL[2].y, exL[2].z, exL[2].w, exH[2].x, exH[2].y, exH[2].z, exH[2].w};
      float xb[8] = {exL[3].x, exL[3].y, exL[3].z, exL[3].w, exH[3].x, exH[3].y, exH[3].z, exH[3].w};
      phase_b(p, bgB, l, w, Yx, attf, umov, vmfragT, zfs + 8192, zrB,
              cw, bw, gw, bbv, lbw, lb16, xa, xb, addx);
    }
    __syncthreads();                          // end: zfs ready for t+1
  }

  if (cg == 0) {
    #pragma unroll
    for (int bi = 0; bi < 2; ++bi) {
      *(float4*)(zout + (size_t)(b0A + bi) * E_ + l * 8)     = *(float4*)&zrA[bi][0];
      *(float4*)(zout + (size_t)(b0A + bi) * E_ + l * 8 + 4) = *(float4*)&zrA[bi][4];
      *(float4*)(zout + (size_t)(b0B + bi) * E_ + l * 8)     = *(float4*)&zrB[bi][0];
      *(float4*)(zout + (size_t)(b0B + bi) * E_ + l * 8 + 4) = *(float4*)&zrB[bi][4];
    }
  }
}

// ---------------- K8: logits = z @ vocab_W + vocab_b (bf16 MFMA) -----------
#define K2_SMEM (128 * ZSTR * 2)

__global__ __launch_bounds__(512, 2) void k_logits(
    const float* __restrict__ z, const float* __restrict__ W,
    const float* __restrict__ bia, float* __restrict__ out)
{
  extern __shared__ short zl[];                 // [128][ZSTR] bf16
  const int tid = threadIdx.x;
  const int btile = blockIdx.x & 1;
  const int vt = blockIdx.x >> 1;
  for (int i = tid; i < 128 * 128; i += 512) {
    int row = i >> 7, c4 = (i & 127) << 2;
    float4 zv = *(const float4*)(z + (size_t)(btile * 128 + row) * E_ + c4);
    short* d = zl + row * ZSTR + c4;
    d[0] = f2bf(zv.x); d[1] = f2bf(zv.y); d[2] = f2bf(zv.z); d[3] = f2bf(zv.w);
  }
  __syncthreads();
  const int lane = tid & 63, w = tid >> 6;
  const int vc = vt * 128 + w * 16 + (lane & 15);
  const int kq = (lane >> 4) * 8;
  f32x4 acc[8];
  #pragma unroll
  for (int rt = 0; rt < 8; ++rt) acc[rt] = (f32x4){0.f, 0.f, 0.f, 0.f};
  for (int ks = 0; ks < 16; ++ks) {
    bf16x8 bf;
    #pragma unroll
    for (int j = 0; j < 8; ++j)
      bf[j] = f2bf(W[(size_t)(ks * 32 + kq + j) * V_ + vc]);
    #pragma unroll
    for (int rt = 0; rt < 8; ++rt) {
      bf16x8 a = *(const bf16x8*)&zl[(rt * 16 + (lane & 15)) * ZSTR + ks * 32 + kq];
      acc[rt] = __builtin_amdgcn_mfma_f32_16x16x32_bf16(a, bf, acc[rt], 0, 0, 0);
    }
  }
  const float bbv = bia[vc];
  #pragma unroll
  for (int rt = 0; rt < 8; ++rt)
    #pragma unroll
    for (int r = 0; r < 4; ++r)
      out[(size_t)(btile * 128 + rt * 16 + (lane >> 4) * 4 + r) * V_ + vc] = acc[rt][r] + bbv;
}

// ---------------- K9: in-place log_softmax over vocab ----------------------
__global__ void k_logsoftmax(float* __restrict__ y)
{
  float* L = y + (size_t)blockIdx.x * V_;
  float m = -3.402823466e+38f, s = 0.f;
  for (int i = threadIdx.x; i < V_; i += 256) {
    float l = L[i];
    if (l > m) { s = s * __expf(m - l) + 1.f; m = l; }
    else       { s += __expf(l - m); }
  }
  #pragma unroll
  for (int k = 1; k < 64; k <<= 1) {
    float m2 = __shfl_xor(m, k, 64);
    float s2 = __shfl_xor(s, k, 64);
    float M = fmaxf(m, m2);
    s = s * __expf(m - M) + s2 * __expf(m2 - M);
    m = M;
  }
  __shared__ float ms[4], ss[4];
  if ((threadIdx.x & 63) == 0) { ms[threadIdx.x >> 6] = m; ss[threadIdx.x >> 6] = s; }
  __syncthreads();
  float M = fmaxf(fmaxf(ms[0], ms[1]), fmaxf(ms[2], ms[3]));
  float S = ss[0] * __expf(ms[0] - M) + ss[1] * __expf(ms[1] - M) +
            ss[2] * __expf(ms[2] - M) + ss[3] * __expf(ms[3] - M);
  const float lse = M + logf(S);
  for (int i = threadIdx.x; i < V_; i += 256) L[i] -= lse;
}

#define SCAN_SMEM 149248

extern "C" void kernel_launch(void* const* d_in, const int* in_sizes, int n_in,
                              void* d_out, int out_size, void* d_ws, size_t ws_size,
                              hipStream_t stream) {
  const float* hidden = (const float*)d_in[0];
  const int*   seq    = (const int*)  d_in[1];
  const float* emb    = (const float*)d_in[2];
  const float* Wq     = (const float*)d_in[3];
  const float* bq     = (const float*)d_in[4];
  const float* Wk     = (const float*)d_in[5];
  const float* bk     = (const float*)d_in[6];
  const float* Wv     = (const float*)d_in[7];
  const float* bv     = (const float*)d_in[8];
  const float* mover  = (const float*)d_in[9];
  const float* gamma  = (const float*)d_in[10];
  const float* beta   = (const float*)d_in[11];
  const float* vocabW = (const float*)d_in[12];
  const float* vocabB = (const float*)d_in[13];

  float* zoutp = (float*)d_out;                 // (256,1,512)
  float* yout  = zoutp + (size_t)B_ * E_;       // (256,1,32000); scratch until k_logits

  // scratch inside yout (all overwritten by k_logits afterwards)
  short*    Wfrag = (short*)yout;               // 65*16*64*8 = 532480 bf16
  float*    A     = yout + 266240;              // 512*512
  float*    Wqk   = A + 262144;                 // 512*16
  float*    cvec  = Wqk + 8192;                 // 512
  float*    lbp   = cvec + 512;                 // 17 (pad 32)
  float*    kmvmS = lbp + 32;                   // 2*16*512
  short*    Yx    = (short*)(kmvmS + 16384);    // [2][16][16][1056] bf16 = 540672
  unsigned* flags = (unsigned*)(Yx + 540672);   // 16 bg x 32 u32 (one 128B line each)

  hipMemsetAsync(flags, 0, 16 * 32 * 4, stream);
  hipLaunchKernelGGL(k_movers, dim3(32), dim3(256), 0, stream, Wk, bk, Wv, bv, mover, kmvmS);
  hipLaunchKernelGGL(k_gemmA,  dim3(1024), dim3(64), 0, stream, Wq, Wk, A);
  hipLaunchKernelGGL(k_wqk,    dim3(512), dim3(64), 0, stream, Wq, kmvmS, Wqk);
  hipLaunchKernelGGL(k_cvec,   dim3(8), dim3(64), 0, stream, Wq, Wk, bq, bk, cvec);
  hipLaunchKernelGGL(k_lb,     dim3(1), dim3(64), 0, stream, bq, bk, kmvmS, lbp);
  hipLaunchKernelGGL(k_pack,   dim3(NT * 16), dim3(64), 0, stream, A, Wv, Wqk, Wfrag);

  hipFuncSetAttribute((const void*)k_scan7, hipFuncAttributeMaxDynamicSharedMemorySize, SCAN_SMEM);
  void* args[] = {(void*)&hidden, (void*)&seq, (void*)&emb,
                  (void*)&gamma, (void*)&beta, (void*)&bv,
                  (void*)&kmvmS, (void*)&cvec, (void*)&lbp, (void*)&Wfrag,
                  (void*)&Yx, (void*)&flags, (void*)&zoutp};
  hipLaunchCooperativeKernel((const void*)k_scan7, dim3(NCG * 8), dim3(512),
                             args, SCAN_SMEM, stream);

  hipFuncSetAttribute((const void*)k_logits, hipFuncAttributeMaxDynamicSharedMemorySize, K2_SMEM);
  hipLaunchKernelGGL(k_logits, dim3(500), dim3(512), K2_SMEM, stream, zoutp, vocabW, vocabB, yout);
  hipLaunchKernelGGL(k_logsoftmax, dim3(256), dim3(256), 0, stream, yout);
}